// Round 9
// baseline (486.895 us; speedup 1.0000x reference)
//
#include <hip/hip_runtime.h>

typedef unsigned short u16;
typedef __attribute__((ext_vector_type(8))) short bf16x8;   // 8 bf16 in 4 VGPRs
typedef __attribute__((ext_vector_type(4))) float f32x4;

__device__ __forceinline__ float bf2f(unsigned int u) {
    union { unsigned int i; float f; } c; c.i = u << 16; return c.f;
}
__device__ __forceinline__ unsigned int f2bf(float f) {
    union { float f; unsigned int i; } c; c.f = f;
    unsigned int x = c.i;
    unsigned int r = x + 0x7FFFu + ((x >> 16) & 1u);
    return r >> 16;  // RNE; finite inputs
}

// ---- 32x32 weight tile convert+transpose (device helper) ----
__device__ __forceinline__ void wconv_tile(const float* __restrict__ W, u16* __restrict__ Wt,
                                           int K, int N, int bx, int by, int t) {
    __shared__ u16 tile[32][36];
    int k0 = by * 32, n0 = bx * 32;
    int r = t >> 3, c4 = (t & 7) * 4;
    float4 v = *(const float4*)(W + (size_t)(k0 + r) * N + n0 + c4);
    tile[r][c4 + 0] = (u16)f2bf(v.x);
    tile[r][c4 + 1] = (u16)f2bf(v.y);
    tile[r][c4 + 2] = (u16)f2bf(v.z);
    tile[r][c4 + 3] = (u16)f2bf(v.w);
    __syncthreads();
    int n = t >> 3, k4 = (t & 7) * 4;
    u16 a0 = tile[k4 + 0][n], a1 = tile[k4 + 1][n];
    u16 a2 = tile[k4 + 2][n], a3 = tile[k4 + 3][n];
    uint2 st;
    st.x = (unsigned)a0 | ((unsigned)a1 << 16);
    st.y = (unsigned)a2 | ((unsigned)a3 << 16);
    *(uint2*)(Wt + (size_t)(n0 + n) * K + k0 + k4) = st;
}

// ---- prep: all 4 weight transposes + bias_table transpose in ONE launch (1D packed grid) ----
__global__ __launch_bounds__(256) void prep_kernel(const float* __restrict__ qkv_w, u16* wq_t,
                                                   const float* __restrict__ proj_w, u16* wp_t,
                                                   const float* __restrict__ fc1_w, u16* w1_t,
                                                   const float* __restrict__ fc2_w, u16* w2_t,
                                                   const float* __restrict__ bias_table, u16* biasT) {
    int id = blockIdx.x, t = threadIdx.x;
    if (id < 768) {                    // qkv_w 512x1536: 48 x 16 tiles
        wconv_tile(qkv_w, wq_t, 512, 1536, id % 48, id / 48, t);
    } else if (id < 1024) {            // proj_w 512x512: 16 x 16
        int l = id - 768;  wconv_tile(proj_w, wp_t, 512, 512, l % 16, l / 16, t);
    } else if (id < 2048) {            // fc1_w 512x2048: 64 x 16
        int l = id - 1024; wconv_tile(fc1_w, w1_t, 512, 2048, l % 64, l / 64, t);
    } else if (id < 3072) {            // fc2_w 2048x512: 16 x 64
        int l = id - 2048; wconv_tile(fc2_w, w2_t, 2048, 512, l % 16, l / 16, t);
    } else {                           // biasT[h][3969] bf16 = bias_table[.,h]
        int l = id - 3072;             // 256 blocks: h = l/16, chunk = l%16
        int h = l / 16, col = (l % 16) * 256 + t;
        if (col < 3969) biasT[(size_t)h * 3969 + col] = (u16)f2bf(bias_table[(size_t)col * 16 + h]);
    }
}

// ---- LN row stats (mu, rsig). 256 thr = 4 rows/block. F32IN: input fp32 else bf16 ----
template <int F32IN>
__global__ __launch_bounds__(256) void ln_stats(const void* __restrict__ xin,
                                                float* __restrict__ mu, float* __restrict__ rsig) {
    int row = blockIdx.x * 4 + (threadIdx.x >> 6);
    int t = threadIdx.x & 63;
    float v[8];
    if (F32IN) {
        const float* xr = (const float*)xin + (size_t)row * 512 + t * 8;
        float4 a = *(const float4*)xr;
        float4 c = *(const float4*)(xr + 4);
        v[0]=a.x; v[1]=a.y; v[2]=a.z; v[3]=a.w; v[4]=c.x; v[5]=c.y; v[6]=c.z; v[7]=c.w;
    } else {
        uint4 u = *(const uint4*)((const u16*)xin + (size_t)row * 512 + t * 8);
        v[0]=bf2f(u.x&0xffff); v[1]=bf2f(u.x>>16); v[2]=bf2f(u.y&0xffff); v[3]=bf2f(u.y>>16);
        v[4]=bf2f(u.z&0xffff); v[5]=bf2f(u.z>>16); v[6]=bf2f(u.w&0xffff); v[7]=bf2f(u.w>>16);
    }
    float s = 0.f, ss = 0.f;
#pragma unroll
    for (int i = 0; i < 8; ++i) { s += v[i]; ss += v[i] * v[i]; }
#pragma unroll
    for (int off = 32; off; off >>= 1) {
        s  += __shfl_down(s, off);
        ss += __shfl_down(ss, off);
    }
    if (t == 0) {
        float m = s * (1.0f / 512.0f);
        float var = ss * (1.0f / 512.0f) - m * m;
        mu[row] = m;
        rsig[row] = rsqrtf(var + 1e-5f);
    }
}

// ---- MFMA GEMM. A: fp32 (AIN=0) or bf16 (AIN=1); optional fused LN on A rows.
// 128x128 tile, BK=32, 4 waves (2x2 of 64x64), 16x16x32 MFMA, fp32 acc.
// RES: 0 none, 1 fp32, 2 bf16. COUT: 0 bf16, 1 fp32. SPLIT: cols<512 -> C, else C2 (qkv).
template <int AIN, int LNA, int ACT, int RES, int COUT, int SPLIT>
__global__ __launch_bounds__(256) void gemm_mfma(const void* __restrict__ A, int lda,
                                                 const float* __restrict__ mu,
                                                 const float* __restrict__ rsig,
                                                 const float* __restrict__ lng,
                                                 const float* __restrict__ lnb,
                                                 const u16* __restrict__ Bt,
                                                 const float* __restrict__ bias,
                                                 const void* __restrict__ res, int ldres,
                                                 void* __restrict__ C, int ldC,
                                                 u16* __restrict__ C2, int ldC2,
                                                 int K) {
    __shared__ u16 As[128 * 56];
    __shared__ u16 Bs[128 * 56];
    int tid = threadIdx.x;
    int bm = blockIdx.y * 128, bn = blockIdx.x * 128;
    int lane = tid & 63, wv = tid >> 6;
    int q = lane >> 4, lr = lane & 15;
    int wr = wv >> 1, wc = wv & 1;
    int sr = tid >> 1, skh = (tid & 1) * 16;

    const u16* Bg = Bt + (size_t)(bn + sr) * K + skh;
    u16* Asw = &As[sr * 56 + skh];
    u16* Bsw = &Bs[sr * 56 + skh];
    const u16* Apf = &As[(wr * 64 + lr) * 56 + q * 8];
    const u16* Bpf = &Bs[(wc * 64 + lr) * 56 + q * 8];

    float mu_r = 0.f, rs_r = 1.f;
    if (LNA) { mu_r = mu[bm + sr]; rs_r = rsig[bm + sr]; }

    f32x4 acc[4][4];
#pragma unroll
    for (int i = 0; i < 4; ++i)
#pragma unroll
        for (int j = 0; j < 4; ++j) acc[i][j] = (f32x4){0.f, 0.f, 0.f, 0.f};

    for (int k0 = 0; k0 < K; k0 += 32) {
        u16 av[16];
        if (AIN == 0) {
            const float* Ag = (const float*)A + (size_t)(bm + sr) * lda + skh + k0;
            float tmp[16];
#pragma unroll
            for (int c = 0; c < 4; ++c) {
                float4 v = *(const float4*)(Ag + c * 4);
                tmp[c*4+0]=v.x; tmp[c*4+1]=v.y; tmp[c*4+2]=v.z; tmp[c*4+3]=v.w;
            }
            if (LNA) {
#pragma unroll
                for (int c = 0; c < 4; ++c) {
                    float4 g4 = *(const float4*)(lng + k0 + skh + c * 4);
                    float4 b4 = *(const float4*)(lnb + k0 + skh + c * 4);
                    tmp[c*4+0] = (tmp[c*4+0]-mu_r)*rs_r*g4.x + b4.x;
                    tmp[c*4+1] = (tmp[c*4+1]-mu_r)*rs_r*g4.y + b4.y;
                    tmp[c*4+2] = (tmp[c*4+2]-mu_r)*rs_r*g4.z + b4.z;
                    tmp[c*4+3] = (tmp[c*4+3]-mu_r)*rs_r*g4.w + b4.w;
                }
            }
#pragma unroll
            for (int j = 0; j < 16; ++j) av[j] = (u16)f2bf(tmp[j]);
        } else {
            const u16* Ag = (const u16*)A + (size_t)(bm + sr) * lda + skh + k0;
            uint4 a0 = *(const uint4*)Ag;
            uint4 a1 = *(const uint4*)(Ag + 8);
            *(uint4*)av = a0; *(uint4*)(av + 8) = a1;
            if (LNA) {
                float tmp[16];
#pragma unroll
                for (int j = 0; j < 16; ++j) tmp[j] = bf2f((unsigned)av[j]);
#pragma unroll
                for (int c = 0; c < 4; ++c) {
                    float4 g4 = *(const float4*)(lng + k0 + skh + c * 4);
                    float4 b4 = *(const float4*)(lnb + k0 + skh + c * 4);
                    tmp[c*4+0] = (tmp[c*4+0]-mu_r)*rs_r*g4.x + b4.x;
                    tmp[c*4+1] = (tmp[c*4+1]-mu_r)*rs_r*g4.y + b4.y;
                    tmp[c*4+2] = (tmp[c*4+2]-mu_r)*rs_r*g4.z + b4.z;
                    tmp[c*4+3] = (tmp[c*4+3]-mu_r)*rs_r*g4.w + b4.w;
                }
#pragma unroll
                for (int j = 0; j < 16; ++j) av[j] = (u16)f2bf(tmp[j]);
            }
        }
        uint4 bv0 = *(const uint4*)(Bg + k0);
        uint4 bv1 = *(const uint4*)(Bg + k0 + 8);
        __syncthreads();
        *(uint4*)Asw = *(uint4*)av; *(uint4*)(Asw + 8) = *(uint4*)(av + 8);
        *(uint4*)Bsw = bv0; *(uint4*)(Bsw + 8) = bv1;
        __syncthreads();
        bf16x8 af[4], bfr[4];
#pragma unroll
        for (int i = 0; i < 4; ++i) af[i] = *(const bf16x8*)(Apf + i * 16 * 56);
#pragma unroll
        for (int j = 0; j < 4; ++j) bfr[j] = *(const bf16x8*)(Bpf + j * 16 * 56);
#pragma unroll
        for (int i = 0; i < 4; ++i)
#pragma unroll
            for (int j = 0; j < 4; ++j)
                acc[i][j] = __builtin_amdgcn_mfma_f32_16x16x32_bf16(af[i], bfr[j], acc[i][j], 0, 0, 0);
    }

    float bv[4];
#pragma unroll
    for (int j = 0; j < 4; ++j)
        bv[j] = bias ? bias[bn + wc * 64 + j * 16 + lr] : 0.f;
#pragma unroll
    for (int i = 0; i < 4; ++i) {
#pragma unroll
        for (int j = 0; j < 4; ++j) {
            int col = bn + wc * 64 + j * 16 + lr;
#pragma unroll
            for (int r = 0; r < 4; ++r) {
                int row = bm + wr * 64 + i * 16 + q * 4 + r;
                float v = acc[i][j][r] + bv[j];
                if (ACT) v = 0.5f * v * (1.0f + erff(v * 0.7071067811865475f));
                if (RES == 1) v += ((const float*)res)[(size_t)row * ldres + col];
                if (RES == 2) v += bf2f((unsigned)((const u16*)res)[(size_t)row * ldres + col]);
                if (SPLIT) {
                    if (col < 512) ((u16*)C)[(size_t)row * ldC + col] = (u16)f2bf(v);
                    else           C2[(size_t)row * ldC2 + col - 512] = (u16)f2bf(v);
                } else if (COUT == 0) {
                    ((u16*)C)[(size_t)row * ldC + col] = (u16)f2bf(v);
                } else {
                    ((float*)C)[(size_t)row * ldC + col] = v;
                }
            }
        }
    }
}

// ---- Flash attention (MFMA), full batch. Q in outQ[8192][512] (in-place O); K/V in KV[8192][1024].
// Bias index computed arithmetically (Swin): idx = (ry-my+31)*63 + (rx-mx+31).
__global__ __launch_bounds__(256) void attn_mfma(u16* __restrict__ outQ,
                                                 const u16* __restrict__ KV,
                                                 const u16* __restrict__ biasT) {
    __shared__ u16 Ks[128][40];
    __shared__ u16 Vt[32][136];
    __shared__ u16 Ps[4][16][136];
    __shared__ u16 biasc[3976];
    int tid = threadIdx.x;
    int qt = blockIdx.x, h = blockIdx.y, z = blockIdx.z;
    u16* Qz = outQ + (size_t)z * 1024 * 512;
    const u16* KVz = KV + (size_t)z * 1024 * 1024;

    for (int i = tid; i < 3969; i += 256) biasc[i] = biasT[(size_t)h * 3969 + i];

    int lane = tid & 63, wv = tid >> 6;
    int q = lane >> 4, m = lane & 15;

    int qrow = qt * 64 + wv * 16 + m;
    bf16x8 qf = *(const bf16x8*)(Qz + (size_t)qrow * 512 + h * 32 + q * 8);

    const float scale = 0.17677669529663687f;
    float mrow[4] = { -1e30f, -1e30f, -1e30f, -1e30f };
    float lrow[4] = { 0.f, 0.f, 0.f, 0.f };
    f32x4 acco[2] = { (f32x4){0.f,0.f,0.f,0.f}, (f32x4){0.f,0.f,0.f,0.f} };

    // per-lane score rows: l = qt*64 + wv*16 + q*4 + r
    int lbase = qt * 64 + wv * 16 + q * 4;

    for (int kt = 0; kt < 8; ++kt) {
        __syncthreads();
        {
            int key = tid >> 1, dh = (tid & 1) * 16;
            const u16* ksrc = KVz + (size_t)(kt * 128 + key) * 1024 + h * 32 + dh;
            uint4 k0 = *(const uint4*)ksrc;
            uint4 k1 = *(const uint4*)(ksrc + 8);
            *(uint4*)&Ks[key][dh] = k0;
            *(uint4*)&Ks[key][dh + 8] = k1;
            const u16* vsrc = KVz + (size_t)(kt * 128 + key) * 1024 + 512 + h * 32 + dh;
            uint4 v0 = *(const uint4*)vsrc;
            uint4 v1 = *(const uint4*)(vsrc + 8);
            u16 tmp[16];
            *(uint4*)tmp = v0; *(uint4*)(tmp + 8) = v1;
#pragma unroll
            for (int j = 0; j < 16; ++j) Vt[dh + j][key] = tmp[j];
        }
        __syncthreads();

        f32x4 s8[8];
#pragma unroll
        for (int t = 0; t < 8; ++t) {
            bf16x8 kf = *(const bf16x8*)&Ks[t * 16 + m][q * 8];
            s8[t] = __builtin_amdgcn_mfma_f32_16x16x32_bf16(
                qf, kf, (f32x4){0.f,0.f,0.f,0.f}, 0, 0, 0);
        }
        // scale + rel-pos bias (arithmetic index; C-layout: row q*4+r, col t*16+m)
#pragma unroll
        for (int t = 0; t < 8; ++t) {
            int key = kt * 128 + t * 16 + m;
            int my = key >> 5, mx = key & 31;
#pragma unroll
            for (int r = 0; r < 4; ++r) {
                int l = lbase + r;
                int idx = ((l >> 5) - my + 31) * 63 + ((l & 31) - mx + 31);
                s8[t][r] = s8[t][r] * scale + bf2f((unsigned)biasc[idx]);
            }
        }
        float alpha[4];
#pragma unroll
        for (int r = 0; r < 4; ++r) {
            float v = s8[0][r];
#pragma unroll
            for (int t = 1; t < 8; ++t) v = fmaxf(v, s8[t][r]);
            v = fmaxf(v, __shfl_xor(v, 1));
            v = fmaxf(v, __shfl_xor(v, 2));
            v = fmaxf(v, __shfl_xor(v, 4));
            v = fmaxf(v, __shfl_xor(v, 8));
            float mn = fmaxf(mrow[r], v);
            alpha[r] = __expf(mrow[r] - mn);
            mrow[r] = mn;
            float sum = 0.f;
#pragma unroll
            for (int t = 0; t < 8; ++t) {
                float p = __expf(s8[t][r] - mn);
                s8[t][r] = p;
                sum += p;
            }
            sum += __shfl_xor(sum, 1);
            sum += __shfl_xor(sum, 2);
            sum += __shfl_xor(sum, 4);
            sum += __shfl_xor(sum, 8);
            lrow[r] = lrow[r] * alpha[r] + sum;
        }
#pragma unroll
        for (int t = 0; t < 8; ++t)
#pragma unroll
            for (int r = 0; r < 4; ++r)
                Ps[wv][q * 4 + r][t * 16 + m] = (u16)f2bf(s8[t][r]);
        __syncthreads();
#pragma unroll
        for (int dt = 0; dt < 2; ++dt)
#pragma unroll
            for (int r = 0; r < 4; ++r) acco[dt][r] *= alpha[r];
#pragma unroll
        for (int c = 0; c < 4; ++c) {
            bf16x8 pf = *(const bf16x8*)&Ps[wv][m][c * 32 + q * 8];
#pragma unroll
            for (int dt = 0; dt < 2; ++dt) {
                bf16x8 vf = *(const bf16x8*)&Vt[dt * 16 + m][c * 32 + q * 8];
                acco[dt] = __builtin_amdgcn_mfma_f32_16x16x32_bf16(pf, vf, acco[dt], 0, 0, 0);
            }
        }
    }
#pragma unroll
    for (int r = 0; r < 4; ++r) {
        int l = lbase + r;
        float inv = 1.0f / lrow[r];
#pragma unroll
        for (int dt = 0; dt < 2; ++dt)
            Qz[(size_t)l * 512 + h * 32 + dt * 16 + m] = (u16)f2bf(acco[dt][r] * inv);
    }
}

extern "C" void kernel_launch(void* const* d_in, const int* in_sizes, int n_in,
                              void* d_out, int out_size, void* d_ws, size_t ws_size,
                              hipStream_t stream) {
    const float* x          = (const float*)d_in[0];
    const float* bias_table = (const float*)d_in[2];
    const float* qkv_w      = (const float*)d_in[3];
    const float* qkv_b      = (const float*)d_in[4];
    const float* proj_w     = (const float*)d_in[5];
    const float* proj_b     = (const float*)d_in[6];
    const float* n1g        = (const float*)d_in[7];
    const float* n1b        = (const float*)d_in[8];
    const float* n2g        = (const float*)d_in[9];
    const float* n2b        = (const float*)d_in[10];
    const float* fc1_w      = (const float*)d_in[11];
    const float* fc1_b      = (const float*)d_in[12];
    const float* fc2_w      = (const float*)d_in[13];
    const float* fc2_b      = (const float*)d_in[14];
    float* out = (float*)d_out;

    // ws (31.7 MB, u16 elems): wq_t@0, wp_t@786432, w1_t@1048576, w2_t@2097152,
    //   x2h[8192][512]@3145728, KV[8192][1024]@7340032 (hid reuses), biasT@15728640,
    //   then fp32 mu1/rs1/mu2/rs2.
    u16* ws16  = (u16*)d_ws;
    u16* wq_t  = ws16;
    u16* wp_t  = ws16 + 786432;
    u16* w1_t  = ws16 + 1048576;
    u16* w2_t  = ws16 + 2097152;
    u16* x2h   = ws16 + 3145728;
    u16* KV    = ws16 + 7340032;
    u16* hid   = KV;
    u16* biasT = ws16 + 15728640;
    float* mu1 = (float*)(ws16 + 15792144);
    float* rs1 = mu1 + 8192;
    float* mu2 = rs1 + 8192;
    float* rs2 = mu2 + 8192;
    u16* outQ  = (u16*)d_out;   // scratch: Q then attn-O (dead before fc2 writes out)

    prep_kernel<<<3328, 256, 0, stream>>>(qkv_w, wq_t, proj_w, wp_t, fc1_w, w1_t,
                                          fc2_w, w2_t, bias_table, biasT);
    ln_stats<1><<<2048, 256, 0, stream>>>(x, mu1, rs1);
    // qkv = LN1(x) @ qkv_w + qkv_b, split: Q -> outQ, K/V -> KV   [8192 x 1536]
    gemm_mfma<0, 1, 0, 0, 0, 1><<<dim3(12, 64), 256, 0, stream>>>(
        x, 512, mu1, rs1, n1g, n1b, wq_t, qkv_b, nullptr, 0, outQ, 512, KV, 1024, 512);
    attn_mfma<<<dim3(16, 16, 8), 256, 0, stream>>>(outQ, KV, biasT);
    // x2(bf16) = attnO @ proj_w + proj_b + x   -> x2h
    gemm_mfma<1, 0, 0, 1, 0, 0><<<dim3(4, 64), 256, 0, stream>>>(
        outQ, 512, nullptr, nullptr, nullptr, nullptr, wp_t, proj_b, x, 512, x2h, 512, nullptr, 0, 512);
    ln_stats<0><<<2048, 256, 0, stream>>>(x2h, mu2, rs2);
    for (int half = 0; half < 2; ++half) {
        size_t ro = (size_t)half * 4096;
        // hid = gelu(LN2(x2) @ fc1_w + fc1_b)   [4096 x 2048]
        gemm_mfma<1, 1, 1, 0, 0, 0><<<dim3(16, 32), 256, 0, stream>>>(
            x2h + ro * 512, 512, mu2 + ro, rs2 + ro, n2g, n2b, w1_t, fc1_b,
            nullptr, 0, hid, 2048, nullptr, 0, 512);
        // out = hid @ fc2_w + fc2_b + x2   (fp32)
        gemm_mfma<1, 0, 0, 2, 1, 0><<<dim3(4, 32), 256, 0, stream>>>(
            hid, 2048, nullptr, nullptr, nullptr, nullptr, w2_t, fc2_b,
            x2h + ro * 512, 512, out + ro * 512, 512, nullptr, 0, 2048);
    }
}

// Round 10
// 477.923 us; speedup vs baseline: 1.0188x; 1.0188x over previous
//
#include <hip/hip_runtime.h>

typedef unsigned short u16;
typedef __attribute__((ext_vector_type(8))) short bf16x8;   // 8 bf16 in 4 VGPRs
typedef __attribute__((ext_vector_type(4))) float f32x4;

__device__ __forceinline__ float bf2f(unsigned int u) {
    union { unsigned int i; float f; } c; c.i = u << 16; return c.f;
}
__device__ __forceinline__ unsigned int f2bf(float f) {
    union { float f; unsigned int i; } c; c.f = f;
    unsigned int x = c.i;
    unsigned int r = x + 0x7FFFu + ((x >> 16) & 1u);
    return r >> 16;  // RNE; finite inputs
}

// ---- 32x32 weight tile convert+transpose (device helper) ----
__device__ __forceinline__ void wconv_tile(const float* __restrict__ W, u16* __restrict__ Wt,
                                           int K, int N, int bx, int by, int t) {
    __shared__ u16 tile[32][36];
    int k0 = by * 32, n0 = bx * 32;
    int r = t >> 3, c4 = (t & 7) * 4;
    float4 v = *(const float4*)(W + (size_t)(k0 + r) * N + n0 + c4);
    tile[r][c4 + 0] = (u16)f2bf(v.x);
    tile[r][c4 + 1] = (u16)f2bf(v.y);
    tile[r][c4 + 2] = (u16)f2bf(v.z);
    tile[r][c4 + 3] = (u16)f2bf(v.w);
    __syncthreads();
    int n = t >> 3, k4 = (t & 7) * 4;
    u16 a0 = tile[k4 + 0][n], a1 = tile[k4 + 1][n];
    u16 a2 = tile[k4 + 2][n], a3 = tile[k4 + 3][n];
    uint2 st;
    st.x = (unsigned)a0 | ((unsigned)a1 << 16);
    st.y = (unsigned)a2 | ((unsigned)a3 << 16);
    *(uint2*)(Wt + (size_t)(n0 + n) * K + k0 + k4) = st;
}

// ---- prep: 4 weight transposes + bias_table transpose, one launch ----
__global__ __launch_bounds__(256) void prep_kernel(const float* __restrict__ qkv_w, u16* wq_t,
                                                   const float* __restrict__ proj_w, u16* wp_t,
                                                   const float* __restrict__ fc1_w, u16* w1_t,
                                                   const float* __restrict__ fc2_w, u16* w2_t,
                                                   const float* __restrict__ bias_table, u16* biasT) {
    int id = blockIdx.x, t = threadIdx.x;
    if (id < 768) {
        wconv_tile(qkv_w, wq_t, 512, 1536, id % 48, id / 48, t);
    } else if (id < 1024) {
        int l = id - 768;  wconv_tile(proj_w, wp_t, 512, 512, l % 16, l / 16, t);
    } else if (id < 2048) {
        int l = id - 1024; wconv_tile(fc1_w, w1_t, 512, 2048, l % 64, l / 64, t);
    } else if (id < 3072) {
        int l = id - 2048; wconv_tile(fc2_w, w2_t, 2048, 512, l % 16, l / 16, t);
    } else {
        int l = id - 3072;
        int h = l / 16, col = (l % 16) * 256 + t;
        if (col < 3969) biasT[(size_t)h * 3969 + col] = (u16)f2bf(bias_table[(size_t)col * 16 + h]);
    }
}

// ---- LN row stats (mu, rsig). 256 thr = 4 rows/block ----
template <int F32IN>
__global__ __launch_bounds__(256) void ln_stats(const void* __restrict__ xin,
                                                float* __restrict__ mu, float* __restrict__ rsig) {
    int row = blockIdx.x * 4 + (threadIdx.x >> 6);
    int t = threadIdx.x & 63;
    float v[8];
    if (F32IN) {
        const float* xr = (const float*)xin + (size_t)row * 512 + t * 8;
        float4 a = *(const float4*)xr;
        float4 c = *(const float4*)(xr + 4);
        v[0]=a.x; v[1]=a.y; v[2]=a.z; v[3]=a.w; v[4]=c.x; v[5]=c.y; v[6]=c.z; v[7]=c.w;
    } else {
        uint4 u = *(const uint4*)((const u16*)xin + (size_t)row * 512 + t * 8);
        v[0]=bf2f(u.x&0xffff); v[1]=bf2f(u.x>>16); v[2]=bf2f(u.y&0xffff); v[3]=bf2f(u.y>>16);
        v[4]=bf2f(u.z&0xffff); v[5]=bf2f(u.z>>16); v[6]=bf2f(u.w&0xffff); v[7]=bf2f(u.w>>16);
    }
    float s = 0.f, ss = 0.f;
#pragma unroll
    for (int i = 0; i < 8; ++i) { s += v[i]; ss += v[i] * v[i]; }
#pragma unroll
    for (int off = 32; off; off >>= 1) {
        s  += __shfl_down(s, off);
        ss += __shfl_down(ss, off);
    }
    if (t == 0) {
        float m = s * (1.0f / 512.0f);
        float var = ss * (1.0f / 512.0f) - m * m;
        mu[row] = m;
        rsig[row] = rsqrtf(var + 1e-5f);
    }
}

// ---- MFMA GEMM. BM = 128 (4 waves 2x2 of 64x64) or 64 (4 waves 2x2 of 32x64).
// A: fp32 (AIN=0) or bf16 (AIN=1); optional fused LN. BN=128, BK=32, 16x16x32 MFMA, fp32 acc.
// RES: 0 none, 1 fp32, 2 bf16. COUT: 0 bf16, 1 fp32. SPLIT: qkv 3-way (Q/K/V).
template <int BM, int AIN, int LNA, int ACT, int RES, int COUT, int SPLIT>
__global__ __launch_bounds__(256) void gemm_mfma(const void* __restrict__ A, int lda,
                                                 const float* __restrict__ mu,
                                                 const float* __restrict__ rsig,
                                                 const float* __restrict__ lng,
                                                 const float* __restrict__ lnb,
                                                 const u16* __restrict__ Bt,
                                                 const float* __restrict__ bias,
                                                 const void* __restrict__ res, int ldres,
                                                 void* __restrict__ C, int ldC,
                                                 u16* __restrict__ Ck, u16* __restrict__ Cv,
                                                 int K) {
    constexpr int NI = BM / 32;                 // row frags per wave
    __shared__ u16 As[BM * 56];
    __shared__ u16 Bs[128 * 56];
    int tid = threadIdx.x;
    int bm = blockIdx.y * BM, bn = blockIdx.x * 128;
    int lane = tid & 63, wv = tid >> 6;
    int q = lane >> 4, lr = lane & 15;
    int wr = wv >> 1, wc = wv & 1;
    // A staging: BM=128 -> 16 u16/thread; BM=64 -> 8 u16/thread
    int sr  = (BM == 128) ? (tid >> 1) : (tid >> 2);
    int skh = (BM == 128) ? ((tid & 1) * 16) : ((tid & 3) * 8);
    constexpr int AE = (BM == 128) ? 16 : 8;
    int srB = tid >> 1, skhB = (tid & 1) * 16;

    const u16* Bg = Bt + (size_t)(bn + srB) * K + skhB;
    u16* Asw = &As[sr * 56 + skh];
    u16* Bsw = &Bs[srB * 56 + skhB];
    const u16* Apf = &As[(wr * (NI * 16) + lr) * 56 + q * 8];
    const u16* Bpf = &Bs[(wc * 64 + lr) * 56 + q * 8];

    float mu_r = 0.f, rs_r = 1.f;
    if (LNA) { mu_r = mu[bm + sr]; rs_r = rsig[bm + sr]; }

    f32x4 acc[NI][4];
#pragma unroll
    for (int i = 0; i < NI; ++i)
#pragma unroll
        for (int j = 0; j < 4; ++j) acc[i][j] = (f32x4){0.f, 0.f, 0.f, 0.f};

    for (int k0 = 0; k0 < K; k0 += 32) {
        u16 av[AE];
        if (AIN == 0) {
            const float* Ag = (const float*)A + (size_t)(bm + sr) * lda + skh + k0;
            float tmp[AE];
#pragma unroll
            for (int c = 0; c < AE / 4; ++c) {
                float4 v = *(const float4*)(Ag + c * 4);
                tmp[c*4+0]=v.x; tmp[c*4+1]=v.y; tmp[c*4+2]=v.z; tmp[c*4+3]=v.w;
            }
            if (LNA) {
#pragma unroll
                for (int c = 0; c < AE / 4; ++c) {
                    float4 g4 = *(const float4*)(lng + k0 + skh + c * 4);
                    float4 b4 = *(const float4*)(lnb + k0 + skh + c * 4);
                    tmp[c*4+0] = (tmp[c*4+0]-mu_r)*rs_r*g4.x + b4.x;
                    tmp[c*4+1] = (tmp[c*4+1]-mu_r)*rs_r*g4.y + b4.y;
                    tmp[c*4+2] = (tmp[c*4+2]-mu_r)*rs_r*g4.z + b4.z;
                    tmp[c*4+3] = (tmp[c*4+3]-mu_r)*rs_r*g4.w + b4.w;
                }
            }
#pragma unroll
            for (int j = 0; j < AE; ++j) av[j] = (u16)f2bf(tmp[j]);
        } else {
            const u16* Ag = (const u16*)A + (size_t)(bm + sr) * lda + skh + k0;
#pragma unroll
            for (int c = 0; c < AE / 8; ++c)
                *(uint4*)(av + c * 8) = *(const uint4*)(Ag + c * 8);
            if (LNA) {
                float tmp[AE];
#pragma unroll
                for (int j = 0; j < AE; ++j) tmp[j] = bf2f((unsigned)av[j]);
#pragma unroll
                for (int c = 0; c < AE / 4; ++c) {
                    float4 g4 = *(const float4*)(lng + k0 + skh + c * 4);
                    float4 b4 = *(const float4*)(lnb + k0 + skh + c * 4);
                    tmp[c*4+0] = (tmp[c*4+0]-mu_r)*rs_r*g4.x + b4.x;
                    tmp[c*4+1] = (tmp[c*4+1]-mu_r)*rs_r*g4.y + b4.y;
                    tmp[c*4+2] = (tmp[c*4+2]-mu_r)*rs_r*g4.z + b4.z;
                    tmp[c*4+3] = (tmp[c*4+3]-mu_r)*rs_r*g4.w + b4.w;
                }
#pragma unroll
                for (int j = 0; j < AE; ++j) av[j] = (u16)f2bf(tmp[j]);
            }
        }
        uint4 bv0 = *(const uint4*)(Bg + k0);
        uint4 bv1 = *(const uint4*)(Bg + k0 + 8);
        __syncthreads();
#pragma unroll
        for (int c = 0; c < AE / 8; ++c)
            *(uint4*)(Asw + c * 8) = *(uint4*)(av + c * 8);
        *(uint4*)Bsw = bv0; *(uint4*)(Bsw + 8) = bv1;
        __syncthreads();
        bf16x8 af[NI], bfr[4];
#pragma unroll
        for (int i = 0; i < NI; ++i) af[i] = *(const bf16x8*)(Apf + i * 16 * 56);
#pragma unroll
        for (int j = 0; j < 4; ++j) bfr[j] = *(const bf16x8*)(Bpf + j * 16 * 56);
#pragma unroll
        for (int i = 0; i < NI; ++i)
#pragma unroll
            for (int j = 0; j < 4; ++j)
                acc[i][j] = __builtin_amdgcn_mfma_f32_16x16x32_bf16(af[i], bfr[j], acc[i][j], 0, 0, 0);
    }

    float bv[4];
#pragma unroll
    for (int j = 0; j < 4; ++j)
        bv[j] = bias ? bias[bn + wc * 64 + j * 16 + lr] : 0.f;
#pragma unroll
    for (int i = 0; i < NI; ++i) {
#pragma unroll
        for (int j = 0; j < 4; ++j) {
            int col = bn + wc * 64 + j * 16 + lr;
#pragma unroll
            for (int r = 0; r < 4; ++r) {
                int row = bm + wr * (NI * 16) + i * 16 + q * 4 + r;
                float v = acc[i][j][r] + bv[j];
                if (ACT) v = 0.5f * v * (1.0f + erff(v * 0.7071067811865475f));
                if (RES == 1) v += ((const float*)res)[(size_t)row * ldres + col];
                if (RES == 2) v += bf2f((unsigned)((const u16*)res)[(size_t)row * ldres + col]);
                if (SPLIT) {
                    if (col < 512)       ((u16*)C)[(size_t)row * 512 + col] = (u16)f2bf(v);
                    else if (col < 1024) Ck[(size_t)row * 512 + col - 512] = (u16)f2bf(v);
                    else                 Cv[(size_t)row * 512 + col - 1024] = (u16)f2bf(v);
                } else if (COUT == 0) {
                    ((u16*)C)[(size_t)row * ldC + col] = (u16)f2bf(v);
                } else {
                    ((float*)C)[(size_t)row * ldC + col] = v;
                }
            }
        }
    }
}

// ---- V transpose: Vbuf[8192][512] -> VT[z][h][d][l] (verified ktrans pattern) ----
__global__ __launch_bounds__(256) void vtrans_kernel(const u16* __restrict__ Vbuf,
                                                     u16* __restrict__ VT) {
    __shared__ u16 tile[32][36];
    int lt = blockIdx.x, h = blockIdx.y, z = blockIdx.z;
    int t = threadIdx.x;
    int l = t >> 3, d4 = (t & 7) * 4;
    uint2 v = *(const uint2*)(Vbuf + ((size_t)(z * 1024 + lt * 32 + l)) * 512 + h * 32 + d4);
    tile[l][d4 + 0] = (u16)(v.x & 0xffff);
    tile[l][d4 + 1] = (u16)(v.x >> 16);
    tile[l][d4 + 2] = (u16)(v.y & 0xffff);
    tile[l][d4 + 3] = (u16)(v.y >> 16);
    __syncthreads();
    int d = t >> 3, l4 = (t & 7) * 4;
    u16 a0 = tile[l4 + 0][d], a1 = tile[l4 + 1][d];
    u16 a2 = tile[l4 + 2][d], a3 = tile[l4 + 3][d];
    uint2 st;
    st.x = (unsigned)a0 | ((unsigned)a1 << 16);
    st.y = (unsigned)a2 | ((unsigned)a3 << 16);
    *(uint2*)(VT + (((size_t)z * 16 + h) * 32 + d) * 1024 + lt * 32 + l4) = st;
}

// ---- Flash attention: 64-key tiles, prefetch, no-max softmax (bounded scores), 5 blocks/CU ----
// Q/O in outQ[8192][512] (in-place); K in Kbuf[8192][512]; V in VT[z][h][d][l].
__global__ __launch_bounds__(256) void attn_mfma(u16* __restrict__ outQ,
                                                 const u16* __restrict__ Kbuf,
                                                 const u16* __restrict__ VT,
                                                 const u16* __restrict__ biasT) {
    __shared__ u16 Ks[64][40];
    __shared__ u16 Vs[32][72];
    __shared__ u16 Ps[4][16][72];
    __shared__ u16 biasc[3976];
    int tid = threadIdx.x;
    int qt = blockIdx.x, h = blockIdx.y, z = blockIdx.z;
    u16* Qz = outQ + (size_t)z * 1024 * 512;
    const u16* Kz = Kbuf + (size_t)z * 1024 * 512;
    const u16* Vz = VT + ((size_t)z * 16 + h) * 32 * 1024;

    for (int i = tid; i < 3969; i += 256) biasc[i] = biasT[(size_t)h * 3969 + i];

    int lane = tid & 63, wv = tid >> 6;
    int q = lane >> 4, m = lane & 15;

    int qrow = qt * 64 + wv * 16 + m;
    bf16x8 qf = *(const bf16x8*)(Qz + (size_t)qrow * 512 + h * 32 + q * 8);

    int lbase = qt * 64 + wv * 16 + q * 4;
    int lidx[4];
#pragma unroll
    for (int r = 0; r < 4; ++r) {
        int l = lbase + r;
        lidx[r] = (l >> 5) * 63 + (l & 31) + 1984;   // + 31*63 + 31
    }

    const float scale = 0.17677669529663687f;
    float lrow[4] = { 0.f, 0.f, 0.f, 0.f };
    f32x4 acco[2] = { (f32x4){0.f,0.f,0.f,0.f}, (f32x4){0.f,0.f,0.f,0.f} };

    int skey = tid >> 2, sdh = (tid & 3) * 8;   // K staging: 64 keys x 32 d
    int svd = tid >> 3, svk = (tid & 7) * 8;    // V staging: 32 d x 64 keys

    uint4 kreg = *(const uint4*)(Kz + (size_t)skey * 512 + h * 32 + sdh);
    uint4 vreg = *(const uint4*)(Vz + (size_t)svd * 1024 + svk);

    for (int kt = 0; kt < 16; ++kt) {
        __syncthreads();                    // previous tile fully consumed
        *(uint4*)&Ks[skey][sdh] = kreg;
        *(uint4*)&Vs[svd][svk] = vreg;
        if (kt < 15) {                      // prefetch next tile (latency hidden by compute)
            kreg = *(const uint4*)(Kz + (size_t)((kt + 1) * 64 + skey) * 512 + h * 32 + sdh);
            vreg = *(const uint4*)(Vz + (size_t)svd * 1024 + (kt + 1) * 64 + svk);
        }
        __syncthreads();                    // tile visible

        f32x4 s8[4];
#pragma unroll
        for (int t = 0; t < 4; ++t) {
            bf16x8 kf = *(const bf16x8*)&Ks[t * 16 + m][q * 8];
            s8[t] = __builtin_amdgcn_mfma_f32_16x16x32_bf16(
                qf, kf, (f32x4){0.f,0.f,0.f,0.f}, 0, 0, 0);
        }
        // scale + bias + exp (no max-shift: scores bounded, softmax shift-invariant)
#pragma unroll
        for (int t = 0; t < 4; ++t) {
            int key = kt * 64 + t * 16 + m;
            int kidx = (key >> 5) * 63 + (key & 31);
#pragma unroll
            for (int r = 0; r < 4; ++r) {
                float b = bf2f((unsigned)biasc[lidx[r] - kidx]);
                s8[t][r] = __expf(fmaf(s8[t][r], scale, b));
            }
        }
        // row sums -> l
#pragma unroll
        for (int r = 0; r < 4; ++r) {
            float sum = s8[0][r] + s8[1][r] + s8[2][r] + s8[3][r];
            sum += __shfl_xor(sum, 1);
            sum += __shfl_xor(sum, 2);
            sum += __shfl_xor(sum, 4);
            sum += __shfl_xor(sum, 8);
            lrow[r] += sum;
        }
        // P -> wave-private LDS (C-layout -> A-layout round trip)
#pragma unroll
        for (int t = 0; t < 4; ++t)
#pragma unroll
            for (int r = 0; r < 4; ++r)
                Ps[wv][q * 4 + r][t * 16 + m] = (u16)f2bf(s8[t][r]);
        asm volatile("s_waitcnt lgkmcnt(0)" ::: "memory");  // wave-local DS drain
        // PV
#pragma unroll
        for (int c = 0; c < 2; ++c) {
            bf16x8 pf = *(const bf16x8*)&Ps[wv][m][c * 32 + q * 8];
#pragma unroll
            for (int dt = 0; dt < 2; ++dt) {
                bf16x8 vf = *(const bf16x8*)&Vs[dt * 16 + m][c * 32 + q * 8];
                acco[dt] = __builtin_amdgcn_mfma_f32_16x16x32_bf16(pf, vf, acco[dt], 0, 0, 0);
            }
        }
    }
#pragma unroll
    for (int r = 0; r < 4; ++r) {
        float inv = 1.0f / lrow[r];
        int l = lbase + r;
#pragma unroll
        for (int dt = 0; dt < 2; ++dt)
            Qz[(size_t)l * 512 + h * 32 + dt * 16 + m] = (u16)f2bf(acco[dt][r] * inv);
    }
}

extern "C" void kernel_launch(void* const* d_in, const int* in_sizes, int n_in,
                              void* d_out, int out_size, void* d_ws, size_t ws_size,
                              hipStream_t stream) {
    const float* x          = (const float*)d_in[0];
    const float* bias_table = (const float*)d_in[2];
    const float* qkv_w      = (const float*)d_in[3];
    const float* qkv_b      = (const float*)d_in[4];
    const float* proj_w     = (const float*)d_in[5];
    const float* proj_b     = (const float*)d_in[6];
    const float* n1g        = (const float*)d_in[7];
    const float* n1b        = (const float*)d_in[8];
    const float* n2g        = (const float*)d_in[9];
    const float* n2b        = (const float*)d_in[10];
    const float* fc1_w      = (const float*)d_in[11];
    const float* fc1_b      = (const float*)d_in[12];
    const float* fc2_w      = (const float*)d_in[13];
    const float* fc2_b      = (const float*)d_in[14];
    float* out = (float*)d_out;

    // ws (~31.7MB, u16 elems): wq_t@0(786432), wp_t@786432(262144), w1_t@1048576(1048576),
    //  w2_t@2097152(1048576), x2h/VT@3145728(4194304), Kbuf@7340032(4194304),
    //  Vbuf@11534336(4194304), hid overlays Kbuf+Vbuf, biasT@15728640(63504), stats after.
    u16* ws16  = (u16*)d_ws;
    u16* wq_t  = ws16;
    u16* wp_t  = ws16 + 786432;
    u16* w1_t  = ws16 + 1048576;
    u16* w2_t  = ws16 + 2097152;
    u16* x2h   = ws16 + 3145728;
    u16* VT    = x2h;                       // x2h dead until proj; VT dead after attn
    u16* Kbuf  = ws16 + 7340032;
    u16* Vbuf  = ws16 + 11534336;
    u16* hid   = Kbuf;                      // K/V dead after attn
    u16* biasT = ws16 + 15728640;
    float* mu1 = (float*)(ws16 + 15792144);
    float* rs1 = mu1 + 8192;
    float* mu2 = rs1 + 8192;
    float* rs2 = mu2 + 8192;
    u16* outQ  = (u16*)d_out;               // bf16 Q/O scratch inside fp32 out buffer

    prep_kernel<<<3328, 256, 0, stream>>>(qkv_w, wq_t, proj_w, wp_t, fc1_w, w1_t,
                                          fc2_w, w2_t, bias_table, biasT);
    ln_stats<1><<<2048, 256, 0, stream>>>(x, mu1, rs1);
    // qkv = LN1(x) @ qkv_w + qkv_b, split Q->outQ, K->Kbuf, V->Vbuf
    gemm_mfma<128, 0, 1, 0, 0, 0, 1><<<dim3(12, 64), 256, 0, stream>>>(
        x, 512, mu1, rs1, n1g, n1b, wq_t, qkv_b, nullptr, 0, outQ, 512, Kbuf, Vbuf, 512);
    vtrans_kernel<<<dim3(32, 16, 8), 256, 0, stream>>>(Vbuf, VT);
    attn_mfma<<<dim3(16, 16, 8), 256, 0, stream>>>(outQ, Kbuf, VT, biasT);
    // x2(bf16) = attnO @ proj_w + proj_b + x
    gemm_mfma<64, 1, 0, 0, 1, 0, 0><<<dim3(4, 128), 256, 0, stream>>>(
        outQ, 512, nullptr, nullptr, nullptr, nullptr, wp_t, proj_b, x, 512,
        x2h, 512, nullptr, nullptr, 512);
    ln_stats<0><<<2048, 256, 0, stream>>>(x2h, mu2, rs2);
    for (int half = 0; half < 2; ++half) {
        size_t ro = (size_t)half * 4096;
        // hid = gelu(LN2(x2) @ fc1_w + fc1_b)
        gemm_mfma<128, 1, 1, 1, 0, 0, 0><<<dim3(16, 32), 256, 0, stream>>>(
            x2h + ro * 512, 512, mu2 + ro, rs2 + ro, n2g, n2b, w1_t, fc1_b,
            nullptr, 0, hid, 2048, nullptr, nullptr, 512);
        // out(fp32) = hid @ fc2_w + fc2_b + x2
        gemm_mfma<64, 1, 0, 0, 2, 1, 0><<<dim3(4, 64), 256, 0, stream>>>(
            hid, 2048, nullptr, nullptr, nullptr, nullptr, w2_t, fc2_b,
            x2h + ro * 512, 512, out + ro * 512, 512, nullptr, nullptr, 2048);
    }
}